// Round 1
// baseline (107.743 us; speedup 1.0000x reference)
//
#include <hip/hip_runtime.h>

typedef unsigned int  u32;
typedef unsigned short u16;
typedef float  f32x4  __attribute__((ext_vector_type(4)));
typedef int    i32x4  __attribute__((ext_vector_type(4)));
typedef __bf16 bf16x8 __attribute__((ext_vector_type(8)));

#define AS1 __attribute__((address_space(1)))
#define AS3 __attribute__((address_space(3)))

__device__ __forceinline__ void gload_lds16(const void* g, void* l) {
  __builtin_amdgcn_global_load_lds((AS1 void*)g, (AS3 void*)l, 16, 0, 0);
}

// Problem constants
constexpr int B_ = 8, T_ = 128, U_ = 64, D_ = 512, V_ = 1024;
constexpr int M_ = B_ * T_ * U_;   // 65536
constexpr int BK = 64;

// ---------------------------------------------------------------------------
// prep: W (V,D) f32 -> bf16 in ws, with the LDS XOR-swizzle pre-applied in the
// global layout (16B chunk c within each 64-col tile stored at c ^ (v&7)),
// so the GEMM can global_load_lds it linearly and read with the same XOR.
// ---------------------------------------------------------------------------
__global__ void prep_w(const float* __restrict__ W, u16* __restrict__ Wb) {
  const int tid = blockIdx.x * 256 + threadIdx.x;   // 65536 threads
  const int v  = tid >> 6;        // row 0..1023
  const int cs = tid & 63;        // source 8-elem chunk 0..63
  const int g  = cs >> 3, cl = cs & 7;
  const float* sp = W + (size_t)v * D_ + cs * 8;
  float4 w0 = *(const float4*)sp;
  float4 w1 = *(const float4*)(sp + 4);
  union { __bf16 h[8]; i32x4 x; } pk;
  pk.h[0] = (__bf16)w0.x; pk.h[1] = (__bf16)w0.y;
  pk.h[2] = (__bf16)w0.z; pk.h[3] = (__bf16)w0.w;
  pk.h[4] = (__bf16)w1.x; pk.h[5] = (__bf16)w1.y;
  pk.h[6] = (__bf16)w1.z; pk.h[7] = (__bf16)w1.w;
  const int dc = g * 8 + (cl ^ (v & 7));
  *(i32x4*)(Wb + (size_t)v * D_ + dc * 8) = pk.x;
}

// lengths pass-through as f32 values (harness reads whole out buffer as f32)
__global__ void tail_k(const int* __restrict__ sl, const int* __restrict__ tl,
                       float* __restrict__ tail) {
  const int t = threadIdx.x;
  if (t < 8)       tail[t] = (float)sl[t];
  else if (t < 16) tail[t] = (float)tl[t - 8];
}

// ---------------------------------------------------------------------------
// Fused joiner GEMM: C[m, v] = sum_d relu(src+tgt) * W[v,d] + bias[v]
// BM=BN=128, BK=64, 256 threads (4 waves, 2x2), wave tile 64x64,
// 4x4 x mfma_f32_16x16x32_bf16 per wave.
// LDS tiles 128 rows x 64 bf16 (128B pitch), 16B-chunk XOR swizzle c ^= row&7.
// ---------------------------------------------------------------------------
template<int USE_WS>
__global__ __launch_bounds__(256, 2) void joiner_gemm(
    const float* __restrict__ src, const float* __restrict__ tgt,
    const u16* __restrict__ Wb, const float* __restrict__ Wf,
    const float* __restrict__ bias, float* __restrict__ out)
{
  __shared__ char As[128 * 128];   // 16 KB
  __shared__ char Bs[128 * 128];   // 16 KB

  const int tid  = threadIdx.x;
  const int lane = tid & 63;
  const int wid  = tid >> 6;
  const int bn   = blockIdx.x & 7;   // 8 N-tiles
  const int bm   = blockIdx.x >> 3;  // 512 M-tiles
  const int bt0  = bm * 2;           // two (b,t) rows per M-tile (U=64)
  const int bb   = bt0 >> 7;         // batch idx (bt0 even -> both rows same b)
  const int sr0  = tid >> 3;         // staging row 0..31
  const int sc8  = tid & 7;          // staging 16B chunk 0..7
  const int wm   = (wid >> 1) * 64;
  const int wn   = (wid & 1) * 64;

  f32x4 acc[4][4] = {};

  const float* srcp0 = src + (size_t)bt0 * D_ + sc8 * 8;
  const float* srcp1 = srcp0 + D_;
  const float* tgtp0 = tgt + ((size_t)bb * U_ + sr0) * D_ + sc8 * 8;
  const float* tgtp1 = tgtp0 + (size_t)32 * D_;

  for (int kt = 0; kt < D_ / BK; ++kt) {
    const int k0 = kt * BK;

    // ---- B tile -> LDS ----
    if (USE_WS) {
      #pragma unroll
      for (int q = 0; q < 4; ++q) {
        const int i    = wid * 4 + q;            // 16 x 1KB stripes
        const int vloc = i * 8 + (lane >> 3);
        const u16* g = Wb + (size_t)(bn * 128 + vloc) * D_ + k0 + (lane & 7) * 8;
        gload_lds16(g, Bs + i * 1024);
      }
    } else {
      #pragma unroll
      for (int j = 0; j < 4; ++j) {
        const int vr = sr0 + 32 * j;
        const float* wp = Wf + (size_t)(bn * 128 + vr) * D_ + k0 + sc8 * 8;
        float4 w0 = *(const float4*)wp;
        float4 w1 = *(const float4*)(wp + 4);
        union { __bf16 h[8]; i32x4 x; } pk;
        pk.h[0] = (__bf16)w0.x; pk.h[1] = (__bf16)w0.y;
        pk.h[2] = (__bf16)w0.z; pk.h[3] = (__bf16)w0.w;
        pk.h[4] = (__bf16)w1.x; pk.h[5] = (__bf16)w1.y;
        pk.h[6] = (__bf16)w1.z; pk.h[7] = (__bf16)w1.w;
        *(i32x4*)(Bs + vr * 128 + ((sc8 ^ (vr & 7)) << 4)) = pk.x;
      }
    }

    // ---- A tile: relu(src_row + tgt_row) -> bf16, swizzled ds_write ----
    // thread covers rows {sr0, sr0+32, sr0+64, sr0+96} at chunk sc8:
    // 2 src rows x 2 tgt rows -> 4 combos, loads halved.
    float4 s0a = *(const float4*)(srcp0 + k0);
    float4 s0b = *(const float4*)(srcp0 + k0 + 4);
    float4 s1a = *(const float4*)(srcp1 + k0);
    float4 s1b = *(const float4*)(srcp1 + k0 + 4);
    float4 t0a = *(const float4*)(tgtp0 + k0);
    float4 t0b = *(const float4*)(tgtp0 + k0 + 4);
    float4 t1a = *(const float4*)(tgtp1 + k0);
    float4 t1b = *(const float4*)(tgtp1 + k0 + 4);
    #pragma unroll
    for (int i = 0; i < 2; ++i) {
      const float4 sa = i ? s1a : s0a;
      const float4 sb = i ? s1b : s0b;
      #pragma unroll
      for (int j = 0; j < 2; ++j) {
        const float4 ta = j ? t1a : t0a;
        const float4 tb = j ? t1b : t0b;
        const int r = i * 64 + j * 32 + sr0;
        union { __bf16 h[8]; i32x4 x; } pk;
        pk.h[0] = (__bf16)fmaxf(sa.x + ta.x, 0.f);
        pk.h[1] = (__bf16)fmaxf(sa.y + ta.y, 0.f);
        pk.h[2] = (__bf16)fmaxf(sa.z + ta.z, 0.f);
        pk.h[3] = (__bf16)fmaxf(sa.w + ta.w, 0.f);
        pk.h[4] = (__bf16)fmaxf(sb.x + tb.x, 0.f);
        pk.h[5] = (__bf16)fmaxf(sb.y + tb.y, 0.f);
        pk.h[6] = (__bf16)fmaxf(sb.z + tb.z, 0.f);
        pk.h[7] = (__bf16)fmaxf(sb.w + tb.w, 0.f);
        *(i32x4*)(As + r * 128 + ((sc8 ^ (r & 7)) << 4)) = pk.x;
      }
    }
    __syncthreads();

    // ---- compute: 2 k-steps x (4 A-frag + 4 B-frag ds_read_b128 + 16 MFMA) ----
    #pragma unroll
    for (int s = 0; s < 2; ++s) {
      const int kc = s * 4 + (lane >> 4);   // 16B k-chunk index
      bf16x8 af[4], bg[4];
      #pragma unroll
      for (int mi = 0; mi < 4; ++mi) {
        const int r = wm + mi * 16 + (lane & 15);
        af[mi] = *(const bf16x8*)(As + r * 128 + ((kc ^ (r & 7)) << 4));
      }
      #pragma unroll
      for (int ni = 0; ni < 4; ++ni) {
        const int n = wn + ni * 16 + (lane & 15);
        bg[ni] = *(const bf16x8*)(Bs + n * 128 + ((kc ^ (n & 7)) << 4));
      }
      #pragma unroll
      for (int mi = 0; mi < 4; ++mi)
        #pragma unroll
        for (int ni = 0; ni < 4; ++ni)
          acc[mi][ni] = __builtin_amdgcn_mfma_f32_16x16x32_bf16(
              af[mi], bg[ni], acc[mi][ni], 0, 0, 0);
    }
    __syncthreads();
  }

  // ---- epilogue: C/D layout col=lane&15, row=(lane>>4)*4+reg ----
  const int col = lane & 15;
  const int r4  = (lane >> 4) * 4;
  float bv[4];
  #pragma unroll
  for (int ni = 0; ni < 4; ++ni) bv[ni] = bias[bn * 128 + wn + ni * 16 + col];
  #pragma unroll
  for (int mi = 0; mi < 4; ++mi) {
    const size_t mrow = (size_t)bm * 128 + wm + mi * 16 + r4;
    float* op0 = out + mrow * V_ + bn * 128 + wn + col;
    #pragma unroll
    for (int ni = 0; ni < 4; ++ni) {
      float* op = op0 + ni * 16;
      const f32x4 v = acc[mi][ni];
      op[0 * V_] = v[0] + bv[ni];
      op[1 * V_] = v[1] + bv[ni];
      op[2 * V_] = v[2] + bv[ni];
      op[3 * V_] = v[3] + bv[ni];
    }
  }
}

extern "C" void kernel_launch(void* const* d_in, const int* in_sizes, int n_in,
                              void* d_out, int out_size, void* d_ws, size_t ws_size,
                              hipStream_t stream) {
  const float* src  = (const float*)d_in[0];
  const int*   sl   = (const int*)d_in[1];
  const float* tgt  = (const float*)d_in[2];
  const int*   tl   = (const int*)d_in[3];
  const float* W    = (const float*)d_in[4];
  const float* bias = (const float*)d_in[5];
  float* out  = (float*)d_out;
  float* tail = out + (size_t)M_ * V_;

  tail_k<<<1, 64, 0, stream>>>(sl, tl, tail);

  if (ws_size >= (size_t)V_ * D_ * sizeof(u16)) {
    prep_w<<<(V_ * D_ / 8) / 256, 256, 0, stream>>>(W, (u16*)d_ws);
    joiner_gemm<1><<<(M_ / 128) * (V_ / 128), 256, 0, stream>>>(
        src, tgt, (const u16*)d_ws, nullptr, bias, out);
  } else {
    joiner_gemm<0><<<(M_ / 128) * (V_ / 128), 256, 0, stream>>>(
        src, tgt, nullptr, W, bias, out);
  }
}